// Round 1
// baseline (35607.355 us; speedup 1.0000x reference)
//
#include <hip/hip_runtime.h>
#include <hip/hip_bf16.h>

// ---------------- problem constants (fixed by reference) ----------------
// B=256, T_MAX=512, H=512, O=128, M=512, F=256, 4H=2048, K_gates=640
#define NBLK 256
#define NTHR 512

typedef __attribute__((ext_vector_type(8))) short bf16x8;  // 8 bf16 (4 VGPRs)
typedef __attribute__((ext_vector_type(4))) float f32x4;
typedef __hip_bfloat16 bf16;

// ---------------- workspace layout (bytes) ----------------
#define WS_BAR    0ull        // 2048 u32 barrier slots (8 KB)
#define WS_BS     8192ull     // 512 i32  bs[t]
#define WS_OFF    10240ull    // 512 i32  exclusive prefix of bs
#define WS_BIASQ  16384ull    // 2048 f32 (b_ih+b_hh, q = 4j+g order)
#define WS_BCAT   24576ull    // 1536 f32 (p1_b1 | p2_b1 | ob1)
#define WS_B2CAT  30720ull    // 257 f32  (p1_b2 | p2_b2 | ob2)
#define WS_CBUF   32768ull    // 256*512 f32 cell state
#define WS_XH     557056ull   // 256*1152 bf16: [x(128) | h_par0(512) | h_par1(512)]
#define WS_ABUF   1146880ull  // 256*1536 bf16: [a1 | a2 | o1]
#define WS_WIHH   1933312ull  // 2048*640 bf16, row q=4j+g: [W_ih row | W_hh row]
#define WS_WCAT   4554752ull  // 1536*512 bf16: [p1_W1 ; p2_W1 ; oW1]
#define WS_W2CAT  6127616ull  // 257*512 bf16: [p1_W2 ; p2_W2 ; oW2]
// total ~6.4 MB

__device__ __forceinline__ float sigm(float x) { return 1.0f / (1.0f + __expf(-x)); }

// grid barrier: release-arrive, relaxed-spin, acquire-exit. slot-per-use, counters
// zeroed each launch by hipMemsetAsync. All NBLK blocks must participate.
__device__ __forceinline__ void gsync(unsigned* bar, int slot) {
  __syncthreads();
  if (threadIdx.x == 0) {
    __hip_atomic_fetch_add(&bar[slot], 1u, __ATOMIC_RELEASE, __HIP_MEMORY_SCOPE_AGENT);
    while (__hip_atomic_load(&bar[slot], __ATOMIC_RELAXED, __HIP_MEMORY_SCOPE_AGENT) < (unsigned)NBLK) {
      __builtin_amdgcn_s_sleep(4);
    }
    (void)__hip_atomic_load(&bar[slot], __ATOMIC_ACQUIRE, __HIP_MEMORY_SCOPE_AGENT);
  }
  __syncthreads();
}

// ---------------- staging kernels ----------------
__global__ void k_wihh(char* ws, const float* __restrict__ Wih, const float* __restrict__ Whh,
                       const float* __restrict__ bih, const float* __restrict__ bhh) {
  const int q = blockIdx.x;            // 0..2047, q = 4j+g
  const int j = q >> 2, g = q & 3;
  const int orig = g * 512 + j;        // gate order i,f,g,o = rows 0..511, 512.., ...
  bf16* Wq = (bf16*)(ws + WS_WIHH);
  float* biasq = (float*)(ws + WS_BIASQ);
  for (int k = threadIdx.x; k < 640; k += 256) {
    float w = (k < 128) ? Wih[orig * 128 + k] : Whh[orig * 512 + (k - 128)];
    Wq[(size_t)q * 640 + k] = __float2bfloat16(w);
  }
  if (threadIdx.x == 0) biasq[q] = bih[orig] + bhh[orig];
}

__global__ void k_wcat(char* ws, const float* w1a, const float* b1a, const float* w1b,
                       const float* b1b, const float* w1c, const float* b1c) {
  const int r = blockIdx.x;            // 0..1535
  const int m = r & 511;
  const float* src = (r < 512) ? w1a : ((r < 1024) ? w1b : w1c);
  const float* bsrc = (r < 512) ? b1a : ((r < 1024) ? b1b : b1c);
  bf16* W = (bf16*)(ws + WS_WCAT);
  float* bc = (float*)(ws + WS_BCAT);
  for (int k = threadIdx.x; k < 512; k += 256)
    W[(size_t)r * 512 + k] = __float2bfloat16(src[m * 512 + k]);
  if (threadIdx.x == 0) bc[r] = bsrc[m];
}

__global__ void k_w2cat(char* ws, const float* w2a, const float* b2a, const float* w2b,
                        const float* b2b, const float* w2c, const float* b2c) {
  const int r = blockIdx.x;            // 0..256
  const float* src; const float* bsrc; int m;
  if (r < 128)      { src = w2a; bsrc = b2a; m = r; }
  else if (r < 256) { src = w2b; bsrc = b2b; m = r - 128; }
  else              { src = w2c; bsrc = b2c; m = 0; }
  bf16* W = (bf16*)(ws + WS_W2CAT);
  float* bb = (float*)(ws + WS_B2CAT);
  for (int k = threadIdx.x; k < 512; k += 256)
    W[(size_t)r * 512 + k] = __float2bfloat16(src[m * 512 + k]);
  if (threadIdx.x == 0) bb[r] = bsrc[m];
}

__global__ void k_h0c0(char* ws, const float* __restrict__ features,
                       const float* __restrict__ Wf2h, const float* __restrict__ bf2h_) {
  const int r = blockIdx.x;            // row 0..255
  __shared__ float feat[256];
  feat[threadIdx.x] = features[r * 256 + threadIdx.x];
  __syncthreads();
  float* cbuf = (float*)(ws + WS_CBUF);
  bf16* xh = (bf16*)(ws + WS_XH);
  for (int n = threadIdx.x; n < 1024; n += 256) {
    float s = bf2h_[n];
    for (int k = 0; k < 256; ++k) s += Wf2h[n * 256 + k] * feat[k];
    const int j = n >> 1;
    if (n & 1) cbuf[r * 512 + j] = s;                                   // c0 = hc[...,1]
    else       xh[(size_t)r * 1152 + 128 + j] = __float2bfloat16(s);    // h0 -> parity 0
  }
  if (threadIdx.x < 128) xh[(size_t)r * 1152 + threadIdx.x] = __float2bfloat16(0.f); // x0 = 0
}

__global__ void k_bs(char* ws, const int* __restrict__ lengths) {
  __shared__ int sl[256];
  __shared__ int sbs[512];
  const int t = threadIdx.x;           // 0..511
  if (t < 256) sl[t] = lengths[t];
  __syncthreads();
  int c = 0;
  for (int b = 0; b < 256; ++b) c += (sl[b] > t) ? 1 : 0;
  sbs[t] = c;
  ((int*)(ws + WS_BS))[t] = c;
  __syncthreads();
  int o = 0;
  for (int u = 0; u < t; ++u) o += sbs[u];
  ((int*)(ws + WS_OFF))[t] = o;
}

// ---------------- main persistent scan kernel ----------------
// Grid 256 blocks x 512 threads, cooperative. 3 barriers / time step.
// P_A: gates = [x|h_t] @ Wq^T (+bias), LSTM pointwise -> h_{t+1}, c   (col-partitioned)
// P_B: [a1|a2|o1] = tanh(h_{t+1} @ Wcat^T + bcat)                     (col-partitioned)
// P_C: p1/p2 = a @ W2^T + b2 (p1 -> outputs + next x), offset dot     (col-partitioned)
__global__ void __launch_bounds__(NTHR) scan_kernel(char* ws, const int* __restrict__ lengths,
                                                    float* __restrict__ out, int N) {
  unsigned* bar = (unsigned*)(ws + WS_BAR);
  const int* bsarr = (const int*)(ws + WS_BS);
  const int* offarr = (const int*)(ws + WS_OFF);
  const float* biasq = (const float*)(ws + WS_BIASQ);
  const float* bcat = (const float*)(ws + WS_BCAT);
  const float* b2cat = (const float*)(ws + WS_B2CAT);
  float* cbuf = (float*)(ws + WS_CBUF);
  bf16* xh = (bf16*)(ws + WS_XH);
  bf16* abuf = (bf16*)(ws + WS_ABUF);
  const short* xhs = (const short*)(ws + WS_XH);
  const short* abufs = (const short*)(ws + WS_ABUF);
  const short* wq = (const short*)(ws + WS_WIHH);
  const short* wcat = (const short*)(ws + WS_WCAT);
  const short* w2 = (const short*)(ws + WS_W2CAT);
  const bf16* w2h = (const bf16*)(ws + WS_W2CAT);

  const int bid = blockIdx.x, tid = threadIdx.x;
  const int wave = tid >> 6, lane = tid & 63;
  const int l15 = lane & 15, l16 = lane >> 4;
  const int koff8 = l16 * 8;
  const int Lmax = lengths[0];         // lengths sorted descending

  float* out_p1 = out;
  float* out_p2 = out + (size_t)N * 128;
  float* out_of = out + (size_t)N * 256;
  float* out_xx = out + (size_t)N * 257;

  __shared__ float lds_g[128 * 16];    // P_A gate-tile transpose

  const int cgA = bid >> 1, rgA = bid & 1;  // P_A: 128 col-groups x 2 row-groups
  int slot = 0;

  for (int t = 0; t < Lmax; ++t) {
    const int bsz = bsarr[t];
    const int base = offarr[t];
    const int parR = (t & 1) * 512;         // h_t region
    const int parW = ((t + 1) & 1) * 512;   // h_{t+1} region

    // ================= P_A: gates + LSTM pointwise =================
    {
      const int row0 = rgA * 128 + wave * 16;
      const int qb = cgA * 16;
      if (row0 < bsz) {
        f32x4 acc = {0.f, 0.f, 0.f, 0.f};
        const int arow = row0 + l15;
        const int wrow = qb + l15;
#pragma unroll
        for (int kk = 0; kk < 20; ++kk) {
          const int k0 = kk * 32;
          const int acol = k0 + koff8 + ((k0 >= 128) ? parR : 0);
          bf16x8 av = *(const bf16x8*)(xhs + (size_t)arow * 1152 + acol);
          bf16x8 bv = *(const bf16x8*)(wq + (size_t)wrow * 640 + k0 + koff8);
          acc = __builtin_amdgcn_mfma_f32_16x16x32_bf16(av, bv, acc, 0, 0, 0);
        }
#pragma unroll
        for (int r = 0; r < 4; ++r)
          lds_g[(wave * 16 + l16 * 4 + r) * 16 + l15] = acc[r];
      }
      __syncthreads();
      {
        const int row = tid >> 2;        // 0..127 block-relative
        const int jj = tid & 3;          // hidden col within col-group
        const int grow = rgA * 128 + row;
        if (grow < bsz) {
          const int cb = jj * 4;
          const float gi = lds_g[row * 16 + cb + 0] + biasq[qb + cb + 0];
          const float gf = lds_g[row * 16 + cb + 1] + biasq[qb + cb + 1];
          const float gg = lds_g[row * 16 + cb + 2] + biasq[qb + cb + 2];
          const float go = lds_g[row * 16 + cb + 3] + biasq[qb + cb + 3];
          const int ci = grow * 512 + cgA * 4 + jj;
          float c = cbuf[ci];
          c = sigm(gf) * c + sigm(gi) * tanhf(gg);
          const float h = sigm(go) * tanhf(c);
          cbuf[ci] = c;
          xh[(size_t)grow * 1152 + 128 + parW + cgA * 4 + jj] = __float2bfloat16(h);
        }
      }
    }
    gsync(bar, slot++);

    // ================= P_B: [a1|a2|o1] = tanh(h' @ Wcat^T + b) =================
    if (bid < 192) {
      const int cg = bid >> 1, rg = bid & 1;   // 96 col-groups x 2 row-groups
      const int row0 = rg * 128 + wave * 16;
      const int cb = cg * 16;
      if (row0 < bsz) {
        f32x4 acc = {0.f, 0.f, 0.f, 0.f};
        const int arow = row0 + l15;
        const int wrow = cb + l15;
#pragma unroll
        for (int kk = 0; kk < 16; ++kk) {
          const int k0 = kk * 32 + koff8;
          bf16x8 av = *(const bf16x8*)(xhs + (size_t)arow * 1152 + 128 + parW + k0);
          bf16x8 bv = *(const bf16x8*)(wcat + (size_t)wrow * 512 + k0);
          acc = __builtin_amdgcn_mfma_f32_16x16x32_bf16(av, bv, acc, 0, 0, 0);
        }
        const int dcol = cb + l15;
        const float bb = bcat[dcol];
#pragma unroll
        for (int r = 0; r < 4; ++r) {
          const int grow = row0 + l16 * 4 + r;
          abuf[(size_t)grow * 1536 + dcol] = __float2bfloat16(tanhf(acc[r] + bb));
        }
      }
    }
    gsync(bar, slot++);

    // ================= P_C: p1 / p2 / offset =================
    if (bid < 32) {
      const int sub = bid >> 1, rg = bid & 1;
      const int row0 = rg * 128 + wave * 16;
      const bool isP2 = sub >= 8;
      const int colb = (sub & 7) * 16;
      const int w2row = (isP2 ? 128 : 0) + colb;
      const int kbase = isP2 ? 512 : 0;
      if (row0 < bsz) {
        f32x4 acc = {0.f, 0.f, 0.f, 0.f};
        const int arow = row0 + l15;
        const int wrow = w2row + l15;
#pragma unroll
        for (int kk = 0; kk < 16; ++kk) {
          const int k0 = kk * 32 + koff8;
          bf16x8 av = *(const bf16x8*)(abufs + (size_t)arow * 1536 + kbase + k0);
          bf16x8 bv = *(const bf16x8*)(w2 + (size_t)wrow * 512 + k0);
          acc = __builtin_amdgcn_mfma_f32_16x16x32_bf16(av, bv, acc, 0, 0, 0);
        }
        const float bb = b2cat[w2row + l15];
        const int col = colb + l15;
#pragma unroll
        for (int r = 0; r < 4; ++r) {
          const int grow = row0 + l16 * 4 + r;
          if (grow < bsz) {
            const float v = acc[r] + bb;
            const size_t orow = (size_t)(base + grow);
            if (!isP2) {
              out_p1[orow * 128 + col] = v;
              out_xx[orow * 128 + col] = v;
              xh[(size_t)grow * 1152 + col] = __float2bfloat16(v);  // x_{t+1}
            } else {
              out_p2[orow * 128 + col] = v;
            }
          }
        }
      }
    } else if (bid < 34) {
      // offset = o1 . oW2 + ob2, 128 rows per block, 4 threads per row
      const int rg = bid & 1;
      const int row = rg * 128 + (tid >> 2);
      const int kq = (tid & 3) * 128;
      if (row < bsz) {
        float s = 0.f;
        for (int k = 0; k < 128; ++k)
          s += __bfloat162float(abuf[(size_t)row * 1536 + 1024 + kq + k]) *
               __bfloat162float(w2h[256 * 512 + kq + k]);
        s += __shfl_xor(s, 1);
        s += __shfl_xor(s, 2);
        if ((tid & 3) == 0) out_of[base + row] = s + b2cat[256];
      }
    }
    gsync(bar, slot++);
  }
}

// ---------------- host ----------------
extern "C" void kernel_launch(void* const* d_in, const int* in_sizes, int n_in,
                              void* d_out, int out_size, void* d_ws, size_t ws_size,
                              hipStream_t stream) {
  const float* features = (const float*)d_in[0];
  const int* lengths = (const int*)d_in[1];
  const float* Wf2h = (const float*)d_in[2];
  const float* bf2h_ = (const float*)d_in[3];
  const float* Wih = (const float*)d_in[4];
  const float* Whh = (const float*)d_in[5];
  const float* bih = (const float*)d_in[6];
  const float* bhh = (const float*)d_in[7];
  const float* p1W1 = (const float*)d_in[8];
  const float* p1b1 = (const float*)d_in[9];
  const float* p1W2 = (const float*)d_in[10];
  const float* p1b2 = (const float*)d_in[11];
  const float* p2W1 = (const float*)d_in[12];
  const float* p2b1 = (const float*)d_in[13];
  const float* p2W2 = (const float*)d_in[14];
  const float* p2b2 = (const float*)d_in[15];
  const float* oW1 = (const float*)d_in[16];
  const float* ob1 = (const float*)d_in[17];
  const float* oW2 = (const float*)d_in[18];
  const float* ob2 = (const float*)d_in[19];

  char* ws = (char*)d_ws;
  float* outp = (float*)d_out;
  int N = out_size / 385;  // outputs: p1[N,128] p2[N,128] offset[N] out[N,128]

  hipMemsetAsync(ws + WS_BAR, 0, 8192, stream);  // barrier counters, every launch
  k_wihh<<<2048, 256, 0, stream>>>(ws, Wih, Whh, bih, bhh);
  k_wcat<<<1536, 256, 0, stream>>>(ws, p1W1, p1b1, p2W1, p2b1, oW1, ob1);
  k_w2cat<<<257, 256, 0, stream>>>(ws, p1W2, p1b2, p2W2, p2b2, oW2, ob2);
  k_h0c0<<<256, 256, 0, stream>>>(ws, features, Wf2h, bf2h_);
  k_bs<<<1, 512, 0, stream>>>(ws, lengths);

  const int* lenv = lengths;
  void* args[] = {&ws, &lenv, &outp, &N};
  hipLaunchCooperativeKernel((const void*)scan_kernel, dim3(NBLK), dim3(NTHR),
                             args, 0, stream);
}

// Round 3
// 13307.014 us; speedup vs baseline: 2.6758x; 2.6758x over previous
//
#include <hip/hip_runtime.h>
#include <hip/hip_bf16.h>

// ================= Design (round 3 = round 2 + staging fix) =================
// 8 independent groups of 32 batch rows; each group = 32 blocks (1/CU, 256 total,
// cooperative). Per step only TWO 32-block barriers (h', a1) via the fold
//   W_ih·p1 = (W_ih·p1W2)·a1 + W_ih·p1b2  (Wfold precomputed)
// so p1/p2/offset output GEMMs run inside the barrier-wait window (off-chain).
// Cell state c: one f32 register per thread. Gates weights (64 cols x K=1024 bf16,
// 128KB) LDS-resident per block with XOR swizzle; W1cat/W2cat streamed from L2.
// Block lb owns gate q-cols [64lb,64lb+64) (q=4j+g), h-cols [16lb,16lb+16),
// acat cols [48lb,48lb+48), out-col tile lb (<17) of 257 = p1|p2|offset.
// r2 BUG (NaN): staging loop only covered 1024B of each 2048B LDS weight row ->
// Wfold half read uninitialized. Fixed: 8192 x 16B chunks.

#define NBLK 256
#define NTHR 512

typedef __attribute__((ext_vector_type(8))) short bf16x8;
typedef __attribute__((ext_vector_type(4))) float f32x4;
typedef __hip_bfloat16 bf16;

// ---------------- workspace layout (bytes) ----------------
#define WS_BAR     0ull        // 8 grp x 1024 slots x u32 = 32768
#define WS_BS      32768ull    // 512 i32
#define WS_OFF     34816ull    // 512 i32
#define WS_BIASQ0  36864ull    // 2048 f32 (b_ih+b_hh, q=4j+g)
#define WS_BIASQF  45056ull    // 2048 f32 (+ W_ih . p1b2)
#define WS_BCAT    53248ull    // 1536 f32
#define WS_B2CAT   59392ull    // 272 f32 (257 + zero pad)
#define WS_C0      61440ull    // 256*512 f32
#define WS_H       585728ull   // 2*256*512 bf16
#define WS_ACAT    1110016ull  // 2*256*1536 bf16 (a1|a2|o1)
#define WS_WQF     2682880ull  // 2048*1024 bf16: [Whh row | Wfold row], q=4j+g
#define WS_W1CAT   6877184ull  // 1536*512 bf16 (p1_W1;p2_W1;oW1)
#define WS_W2CAT   8450048ull  // 272*512 bf16 (p1_W2;p2_W2;oW2;zeros)
// end ~8.73 MB

__device__ __forceinline__ float sigm(float x) { return 1.0f / (1.0f + __expf(-x)); }
__device__ __forceinline__ unsigned short f2bu(float x) {
  bf16 b = __float2bfloat16(x);
  return *(unsigned short*)&b;
}

// ---------------- staging kernels ----------------
// WQF: row q=4j+g: [Whh[orig] (512) | Wfold[orig] (512)], Wfold = Wih @ p1W2
__global__ void k_fold(char* ws, const float* __restrict__ Wih, const float* __restrict__ Whh,
                       const float* __restrict__ bih, const float* __restrict__ bhh,
                       const float* __restrict__ p1W2, const float* __restrict__ p1b2) {
  const int q = blockIdx.x;            // 0..2047
  const int j = q >> 2, g = q & 3;
  const int orig = g * 512 + j;
  __shared__ float wih[128];
  if (threadIdx.x < 128) wih[threadIdx.x] = Wih[orig * 128 + threadIdx.x];
  __syncthreads();
  bf16* Wq = (bf16*)(ws + WS_WQF);
  for (int k = threadIdx.x; k < 512; k += 256)
    Wq[(size_t)q * 1024 + k] = __float2bfloat16(Whh[orig * 512 + k]);
  for (int m = threadIdx.x; m < 512; m += 256) {
    float s = 0.f;
    for (int o = 0; o < 128; ++o) s += wih[o] * p1W2[o * 512 + m];
    Wq[(size_t)q * 1024 + 512 + m] = __float2bfloat16(s);
  }
  if (threadIdx.x == 0) {
    float b0 = bih[orig] + bhh[orig];
    ((float*)(ws + WS_BIASQ0))[q] = b0;
    float s = 0.f;
    for (int o = 0; o < 128; ++o) s += wih[o] * p1b2[o];
    ((float*)(ws + WS_BIASQF))[q] = b0 + s;
  }
}

__global__ void k_w1cat(char* ws, const float* w1a, const float* b1a, const float* w1b,
                        const float* b1b, const float* w1c, const float* b1c) {
  const int r = blockIdx.x;            // 0..1535
  const int m = r & 511;
  const float* src = (r < 512) ? w1a : ((r < 1024) ? w1b : w1c);
  const float* bsrc = (r < 512) ? b1a : ((r < 1024) ? b1b : b1c);
  bf16* W = (bf16*)(ws + WS_W1CAT);
  for (int k = threadIdx.x; k < 512; k += 256)
    W[(size_t)r * 512 + k] = __float2bfloat16(src[m * 512 + k]);
  if (threadIdx.x == 0) ((float*)(ws + WS_BCAT))[r] = bsrc[m];
}

__global__ void k_w2cat(char* ws, const float* w2a, const float* b2a, const float* w2b,
                        const float* b2b, const float* w2c, const float* b2c) {
  const int r = blockIdx.x;            // 0..271
  bf16* W = (bf16*)(ws + WS_W2CAT);
  float* bb = (float*)(ws + WS_B2CAT);
  const float* src = nullptr; const float* bsrc = nullptr; int m = 0;
  if (r < 128)      { src = w2a; bsrc = b2a; m = r; }
  else if (r < 256) { src = w2b; bsrc = b2b; m = r - 128; }
  else if (r == 256){ src = w2c; bsrc = b2c; m = 0; }
  for (int k = threadIdx.x; k < 512; k += 256)
    W[(size_t)r * 512 + k] = src ? __float2bfloat16(src[m * 512 + k]) : __float2bfloat16(0.f);
  if (threadIdx.x == 0) bb[r] = src ? bsrc[m] : 0.f;
}

__global__ void k_h0c0(char* ws, const float* __restrict__ features,
                       const float* __restrict__ Wf2h, const float* __restrict__ bf2h_) {
  const int r = blockIdx.x;            // 0..255
  __shared__ float feat[256];
  feat[threadIdx.x] = features[r * 256 + threadIdx.x];
  __syncthreads();
  float* C0 = (float*)(ws + WS_C0);
  bf16* H0 = (bf16*)(ws + WS_H);       // parity 0
  for (int n = threadIdx.x; n < 1024; n += 256) {
    float s = bf2h_[n];
    for (int k = 0; k < 256; ++k) s += Wf2h[n * 256 + k] * feat[k];
    const int j = n >> 1;
    if (n & 1) C0[r * 512 + j] = s;
    else       H0[(size_t)r * 512 + j] = __float2bfloat16(s);
  }
}

__global__ void k_bs(char* ws, const int* __restrict__ lengths) {
  __shared__ int sl[256];
  __shared__ int sbs[512];
  const int t = threadIdx.x;
  if (t < 256) sl[t] = lengths[t];
  __syncthreads();
  int c = 0;
  for (int b = 0; b < 256; ++b) c += (sl[b] > t) ? 1 : 0;
  sbs[t] = c;
  ((int*)(ws + WS_BS))[t] = c;
  __syncthreads();
  int o = 0;
  for (int u = 0; u < t; ++u) o += sbs[u];
  ((int*)(ws + WS_OFF))[t] = o;
}

// ---------------- output-phase GEMM (off-chain, runs in barrier window) ----------------
__device__ __forceinline__ void do_outs(int tm1, const short* __restrict__ Acur, int R0,
                                        int rt2, int l15, int l16, int tile,
                                        const short* __restrict__ W2, const float* __restrict__ b2cat,
                                        const int* __restrict__ bsarr, const int* __restrict__ offarr,
                                        float* __restrict__ out, int N) {
  const int kb = tile < 8 ? 0 : (tile < 16 ? 512 : 1024);
  const int wrow = tile * 16 + l15;    // <= 271 (zero-padded rows past 256)
  const short* ar = Acur + (size_t)(R0 + rt2 * 16 + l15) * 1536 + kb + l16 * 8;
  const short* wr = W2 + (size_t)wrow * 512 + l16 * 8;
  f32x4 acc = {0.f, 0.f, 0.f, 0.f};
#pragma unroll
  for (int kk = 0; kk < 16; ++kk) {
    bf16x8 av = *(const bf16x8*)(ar + kk * 32);
    bf16x8 bv = *(const bf16x8*)(wr + kk * 32);
    acc = __builtin_amdgcn_mfma_f32_16x16x32_bf16(av, bv, acc, 0, 0, 0);
  }
  const float bb = b2cat[wrow];
  const int bsz = bsarr[tm1], base = offarr[tm1];
  const int col = tile * 16 + l15;
  float* out_p1 = out;
  float* out_p2 = out + (size_t)N * 128;
  float* out_of = out + (size_t)N * 256;
  float* out_xx = out + (size_t)N * 257;
#pragma unroll
  for (int r = 0; r < 4; ++r) {
    const int R = R0 + rt2 * 16 + l16 * 4 + r;
    if (R < bsz) {
      const float v = acc[r] + bb;
      const size_t orow = (size_t)(base + R);
      if (col < 128)      { out_p1[orow * 128 + col] = v; out_xx[orow * 128 + col] = v; }
      else if (col < 256) { out_p2[orow * 128 + col - 128] = v; }
      else if (l15 == 0)  { out_of[orow] = v; }
    }
  }
}

// ---------------- main persistent scan kernel ----------------
__global__ void __launch_bounds__(NTHR) scan_kernel(char* ws, const int* __restrict__ lengths,
                                                    float* __restrict__ out, int N) {
  extern __shared__ char smem[];               // [0,131072): gates W slice; then 32x64 f32
  float* ldsg = (float*)(smem + 131072);

  const int bid = blockIdx.x, tid = threadIdx.x;
  const int grp = bid >> 5, lb = bid & 31;
  const int R0 = grp * 32;
  const int wave = tid >> 6, lane = tid & 63;
  const int l15 = lane & 15, l16 = lane >> 4;

  unsigned* barG = (unsigned*)(ws + WS_BAR) + grp * 1024;
  const int* bsarr = (const int*)(ws + WS_BS);
  const int* offarr = (const int*)(ws + WS_OFF);
  const float* biasq0 = (const float*)(ws + WS_BIASQ0);
  const float* biasqF = (const float*)(ws + WS_BIASQF);
  const float* bcat = (const float*)(ws + WS_BCAT);
  const float* b2cat = (const float*)(ws + WS_B2CAT);
  const float* C0 = (const float*)(ws + WS_C0);
  short* Hb = (short*)(ws + WS_H);             // [2][256][512]
  short* Ab = (short*)(ws + WS_ACAT);          // [2][256][1536]
  const short* WQF = (const short*)(ws + WS_WQF);
  const short* W1 = (const short*)(ws + WS_W1CAT);
  const short* W2 = (const short*)(ws + WS_W2CAT);

  // prologue: stage gates weight slice into LDS, XOR-swizzled.
  // 64 rows x 2048B; 8192 chunks of 16B (r2 bug: only covered 1024B/row).
  for (int idx = tid; idx < 8192; idx += NTHR) {
    const int r = idx >> 7, c = idx & 127;
    int4 v = *(const int4*)(WQF + ((size_t)(64 * lb + r) * 1024 + c * 8));
    *(int4*)(smem + (r * 2048 + ((c * 16) ^ ((r & 7) << 4)))) = v;
  }
  const int Lr = tid >> 4, lj = tid & 15;
  float c_reg = C0[(R0 + Lr) * 512 + lb * 16 + lj];
  float b0_[4], bF_[4];
#pragma unroll
  for (int g = 0; g < 4; ++g) {
    const int q = lb * 64 + lj * 4 + g;
    b0_[g] = biasq0[q];
    bF_[g] = biasqF[q];
  }
  const int Lg = lengths[R0];                  // lengths sorted desc -> group max
  const int ct = wave & 3, rt = wave >> 2;     // phase-A wave tile
  __syncthreads();

  for (int t = 0; t < Lg; ++t) {
    const int par = t & 1, parn = par ^ 1;
    const short* Hcur = Hb + par * (256 * 512);
    const short* Acur = Ab + par * (256 * 1536);

    // ---- phase A: gates = Whh.h + Wfold.a1 (K=1024), per wave one 16x16 tile ----
    f32x4 acc = {0.f, 0.f, 0.f, 0.f};
    {
      const int lq = ct * 16 + l15;
      const char* wb = smem + lq * 2048;
      const int xr = (lq & 7) << 4;
      const short* ar = Hcur + (size_t)(R0 + rt * 16 + l15) * 512 + l16 * 8;
#pragma unroll 8
      for (int kk = 0; kk < 16; ++kk) {
        bf16x8 av = *(const bf16x8*)(ar + kk * 32);
        bf16x8 bv = *(const bf16x8*)(wb + ((kk * 64 + l16 * 16) ^ xr));
        acc = __builtin_amdgcn_mfma_f32_16x16x32_bf16(av, bv, acc, 0, 0, 0);
      }
      if (t > 0) {
        const short* ar2 = Acur + (size_t)(R0 + rt * 16 + l15) * 1536 + l16 * 8;
#pragma unroll 8
        for (int kk = 0; kk < 16; ++kk) {
          bf16x8 av = *(const bf16x8*)(ar2 + kk * 32);
          bf16x8 bv = *(const bf16x8*)(wb + (((kk + 16) * 64 + l16 * 16) ^ xr));
          acc = __builtin_amdgcn_mfma_f32_16x16x32_bf16(av, bv, acc, 0, 0, 0);
        }
      }
    }
#pragma unroll
    for (int r = 0; r < 4; ++r)
      ldsg[(rt * 16 + l16 * 4 + r) * 64 + ct * 16 + l15] = acc[r];
    __syncthreads();

    // ---- pointwise LSTM, c in register, h' -> H[parn] ----
    {
      const float* gv = ldsg + Lr * 64 + lj * 4;
      const float gi = gv[0] + (t ? bF_[0] : b0_[0]);
      const float gf = gv[1] + (t ? bF_[1] : b0_[1]);
      const float gg = gv[2] + (t ? bF_[2] : b0_[2]);
      const float go = gv[3] + (t ? bF_[3] : b0_[3]);
      c_reg = sigm(gf) * c_reg + sigm(gi) * tanhf(gg);
      const float h = sigm(go) * tanhf(c_reg);
      const float hp = __shfl_xor(h, 1);
      if ((lj & 1) == 0) {
        const unsigned v = (unsigned)f2bu(h) | ((unsigned)f2bu(hp) << 16);
        *(unsigned*)(Hb + parn * (256 * 512) + (size_t)(R0 + Lr) * 512 + lb * 16 + lj) = v;
      }
    }

    // ---- arrive A (release flushes h' to coherence point) ----
    __syncthreads();
    if (tid == 0)
      __hip_atomic_fetch_add(&barG[t * 2], 1u, __ATOMIC_RELEASE, __HIP_MEMORY_SCOPE_AGENT);

    // ---- off-chain outputs for step t-1 (overlap with barrier wait) ----
    if (t > 0 && lb < 17 && wave < 2)
      do_outs(t - 1, Acur, R0, wave, l15, l16, lb, W2, b2cat, bsarr, offarr, out, N);

    // ---- wait A ----
    if (tid == 0) {
      while (__hip_atomic_load(&barG[t * 2], __ATOMIC_RELAXED, __HIP_MEMORY_SCOPE_AGENT) < 32u)
        __builtin_amdgcn_s_sleep(2);
      (void)__hip_atomic_load(&barG[t * 2], __ATOMIC_ACQUIRE, __HIP_MEMORY_SCOPE_AGENT);
    }
    __syncthreads();

    // ---- phase B: acat = tanh(W1cat . h' + b), 48 cols/block, 6 wave tiles ----
    if (wave < 6) {
      const int ct3 = wave % 3, rt3 = wave / 3;
      const int cb = lb * 48 + ct3 * 16;
      const short* hr = Hb + parn * (256 * 512) + (size_t)(R0 + rt3 * 16 + l15) * 512 + l16 * 8;
      const short* wr = W1 + (size_t)(cb + l15) * 512 + l16 * 8;
      f32x4 a3 = {0.f, 0.f, 0.f, 0.f};
#pragma unroll 8
      for (int kk = 0; kk < 16; ++kk) {
        bf16x8 av = *(const bf16x8*)(hr + kk * 32);
        bf16x8 bv = *(const bf16x8*)(wr + kk * 32);
        a3 = __builtin_amdgcn_mfma_f32_16x16x32_bf16(av, bv, a3, 0, 0, 0);
      }
      const float bb = bcat[cb + l15];
      short* aout = Ab + parn * (256 * 1536);
#pragma unroll
      for (int r = 0; r < 4; ++r) {
        const float v = tanhf(a3[r] + bb);
        const float vp = __shfl_xor(v, 1);
        if ((l15 & 1) == 0) {
          const unsigned pv = (unsigned)f2bu(v) | ((unsigned)f2bu(vp) << 16);
          *(unsigned*)(aout + (size_t)(R0 + rt3 * 16 + l16 * 4 + r) * 1536 + cb + l15) = pv;
        }
      }
    }

    // ---- barrier B (a1 visible for next gates) ----
    __syncthreads();
    if (tid == 0) {
      __hip_atomic_fetch_add(&barG[t * 2 + 1], 1u, __ATOMIC_RELEASE, __HIP_MEMORY_SCOPE_AGENT);
      while (__hip_atomic_load(&barG[t * 2 + 1], __ATOMIC_RELAXED, __HIP_MEMORY_SCOPE_AGENT) < 32u)
        __builtin_amdgcn_s_sleep(2);
      (void)__hip_atomic_load(&barG[t * 2 + 1], __ATOMIC_ACQUIRE, __HIP_MEMORY_SCOPE_AGENT);
    }
    __syncthreads();
  }

  // epilogue: outputs for the final step (a-cat parity Lg&1, written by last phase B)
  if (lb < 17 && wave < 2)
    do_outs(Lg - 1, Ab + (Lg & 1) * (256 * 1536), R0, wave, l15, l16, lb, W2, b2cat,
            bsarr, offarr, out, N);
}

// ---------------- host ----------------
extern "C" void kernel_launch(void* const* d_in, const int* in_sizes, int n_in,
                              void* d_out, int out_size, void* d_ws, size_t ws_size,
                              hipStream_t stream) {
  const float* features = (const float*)d_in[0];
  const int* lengths = (const int*)d_in[1];
  const float* Wf2h = (const float*)d_in[2];
  const float* bf2h_ = (const float*)d_in[3];
  const float* Wih = (const float*)d_in[4];
  const float* Whh = (const float*)d_in[5];
  const float* bih = (const float*)d_in[6];
  const float* bhh = (const float*)d_in[7];
  const float* p1W1 = (const float*)d_in[8];
  const float* p1b1 = (const float*)d_in[9];
  const float* p1W2 = (const float*)d_in[10];
  const float* p1b2 = (const float*)d_in[11];
  const float* p2W1 = (const float*)d_in[12];
  const float* p2b1 = (const float*)d_in[13];
  const float* p2W2 = (const float*)d_in[14];
  const float* p2b2 = (const float*)d_in[15];
  const float* oW1 = (const float*)d_in[16];
  const float* ob1 = (const float*)d_in[17];
  const float* oW2 = (const float*)d_in[18];
  const float* ob2 = (const float*)d_in[19];

  char* ws = (char*)d_ws;
  float* outp = (float*)d_out;
  int N = out_size / 385;

  hipMemsetAsync(ws + WS_BAR, 0, 32768, stream);
  k_fold<<<2048, 256, 0, stream>>>(ws, Wih, Whh, bih, bhh, p1W2, p1b2);
  k_w1cat<<<1536, 256, 0, stream>>>(ws, p1W1, p1b1, p2W1, p2b1, oW1, ob1);
  k_w2cat<<<272, 256, 0, stream>>>(ws, p1W2, p1b2, p2W2, p2b2, oW2, ob2);
  k_h0c0<<<256, 256, 0, stream>>>(ws, features, Wf2h, bf2h_);
  k_bs<<<1, 512, 0, stream>>>(ws, lengths);

  hipFuncSetAttribute((const void*)scan_kernel,
                      hipFuncAttributeMaxDynamicSharedMemorySize, 139264);

  const int* lenv = lengths;
  void* args[] = {&ws, &lenv, &outp, &N};
  hipLaunchCooperativeKernel((const void*)scan_kernel, dim3(NBLK), dim3(NTHR),
                             args, 139264, stream);
}